// Round 1
// 2517.877 us; speedup vs baseline: 1.2882x; 1.2882x over previous
//
#include <hip/hip_runtime.h>
#include <hip/hip_bf16.h>
#include <math.h>

// GPT forward: B=1, T=2048, D=1024, L=4, H=16, HD=64, MLP=4096, V=50257
#define TT   2048
#define DD   1024
#define NL   4
#define NH   16
#define HDIM 64
#define VV   50257
#define DMLP 4096

typedef __bf16 bf16_t;
typedef __bf16 bf16x8 __attribute__((ext_vector_type(8)));
typedef __bf16 bf16x4 __attribute__((ext_vector_type(4)));
typedef float  f32x4  __attribute__((ext_vector_type(4)));

// ---------------- reductions (block = 256 = 4 waves) ----------------
__device__ inline float block_reduce_sum(float v) {
    __shared__ float sbuf[4];
#pragma unroll
    for (int o = 32; o > 0; o >>= 1) v += __shfl_down(v, o, 64);
    int w = threadIdx.x >> 6, lane = threadIdx.x & 63;
    __syncthreads();
    if (lane == 0) sbuf[w] = v;
    __syncthreads();
    return sbuf[0] + sbuf[1] + sbuf[2] + sbuf[3];
}

__device__ inline float block_reduce_max(float v) {
    __shared__ float mbuf[4];
#pragma unroll
    for (int o = 32; o > 0; o >>= 1) v = fmaxf(v, __shfl_down(v, o, 64));
    int w = threadIdx.x >> 6, lane = threadIdx.x & 63;
    __syncthreads();
    if (lane == 0) mbuf[w] = v;
    __syncthreads();
    return fmaxf(fmaxf(mbuf[0], mbuf[1]), fmaxf(mbuf[2], mbuf[3]));
}

// ---------------- async global -> LDS, 16B per lane ----------------
__device__ __forceinline__ void async16(const bf16_t* g, bf16_t* l) {
    __builtin_amdgcn_global_load_lds(
        (const __attribute__((address_space(1))) unsigned int*)g,
        (__attribute__((address_space(3))) unsigned int*)l,
        16, 0, 0);
}

// ---------------- weight convert+transpose: W[K][N] f32 -> Wt[N][K] bf16 ----------------
__global__ void trans_w_kernel(const float* __restrict__ in, bf16_t* __restrict__ out,
                               int K, int N, long inStride, long outStride) {
    __shared__ float tile[32][33];
    long zin  = (long)blockIdx.z * inStride;
    long zout = (long)blockIdx.z * outStride;
    int tx = threadIdx.x, ty = threadIdx.y;
    int n = blockIdx.x * 32 + tx;
    int k0 = blockIdx.y * 32;
#pragma unroll
    for (int i = 0; i < 4; i++)
        tile[ty + i * 8][tx] = in[zin + (long)(k0 + ty + i * 8) * N + n];
    __syncthreads();
    int k = k0 + tx;
#pragma unroll
    for (int i = 0; i < 4; i++) {
        int nn = blockIdx.x * 32 + ty + i * 8;
        out[zout + (long)nn * K + k] = (bf16_t)tile[tx][ty + i * 8];
    }
}

// ---------------- f32 -> bf16 elementwise (x4) ----------------
__global__ void cvt_kernel(const float* __restrict__ in, bf16_t* __restrict__ out, long n4) {
    long i = (long)blockIdx.x * 256 + threadIdx.x;
    if (i >= n4) return;
    float4 v = *(const float4*)(in + i * 4);
    bf16x4 o;
    o[0] = (bf16_t)v.x; o[1] = (bf16_t)v.y; o[2] = (bf16_t)v.z; o[3] = (bf16_t)v.w;
    *(bf16x4*)(out + i * 4) = o;
}

// ---------------- embedding gather (fp32) ----------------
__global__ void gather_kernel(const int* __restrict__ ids, const float* __restrict__ emb,
                              float* __restrict__ x) {
    int row = blockIdx.x;
    int id = ids[row];
    const float4* src = (const float4*)(emb + (long)id * DD);
    float4* dst = (float4*)(x + (long)row * DD);
    dst[threadIdx.x] = src[threadIdx.x];
}

// ---------------- LayerNorm fp32 in -> bf16 out, one block per row ----------------
__global__ __launch_bounds__(256) void ln_kernel(const float* __restrict__ x,
                                                 const float* __restrict__ g,
                                                 const float* __restrict__ b,
                                                 bf16_t* __restrict__ out) {
    int row = blockIdx.x, tid = threadIdx.x;
    float4 v = *(const float4*)(x + (long)row * DD + tid * 4);
    float s = v.x + v.y + v.z + v.w;
    s = block_reduce_sum(s);
    float mean = s * (1.0f / DD);
    float dx = v.x - mean, dy = v.y - mean, dz = v.z - mean, dw = v.w - mean;
    float sq = dx * dx + dy * dy + dz * dz + dw * dw;
    sq = block_reduce_sum(sq);
    float inv = rsqrtf(sq * (1.0f / DD) + 1e-5f);
    float4 gv = *(const float4*)(g + tid * 4);
    float4 bv = *(const float4*)(b + tid * 4);
    bf16x4 o;
    o[0] = (bf16_t)(dx * inv * gv.x + bv.x);
    o[1] = (bf16_t)(dy * inv * gv.y + bv.y);
    o[2] = (bf16_t)(dz * inv * gv.z + bv.z);
    o[3] = (bf16_t)(dw * inv * gv.w + bv.w);
    *(bf16x4*)(out + (long)row * DD + tid * 4) = o;
}

// ---------------- RoPE on q,k (in-place, pairwise) + fold 1/sqrt(HD) into q ----------------
__global__ void rope_kernel(bf16_t* __restrict__ qkv) {
    int t = blockIdx.x;
    int pIdx = blockIdx.y * 256 + threadIdx.x;   // 0..511 : (head, i<32)
    int h = pIdx >> 5, i = pIdx & 31;
    float invf = powf(10000.0f, -(float)i * (1.0f / 32.0f));
    float ang = (float)t * invf;
    float s, c;
    sincosf(ang, &s, &c);
    long base = (long)t * 3072 + h * 64 + i;
    float q1 = (float)qkv[base], q2 = (float)qkv[base + 32];
    qkv[base]      = (bf16_t)((q1 * c - q2 * s) * 0.125f);
    qkv[base + 32] = (bf16_t)((q2 * c + q1 * s) * 0.125f);
    float k1 = (float)qkv[base + 1024], k2 = (float)qkv[base + 1056];
    qkv[base + 1024] = (bf16_t)(k1 * c - k2 * s);
    qkv[base + 1056] = (bf16_t)(k2 * c + k1 * s);
}

// ---------------- per-head V transpose: v[t][d] -> vT[d][t] (d = h*64+dd) ----------------
__global__ void trans_v_kernel(const bf16_t* __restrict__ qkv, bf16_t* __restrict__ vT) {
    __shared__ bf16_t tile[32][33];
    int t0 = blockIdx.x * 32, d0 = blockIdx.y * 32;
    int tx = threadIdx.x, ty = threadIdx.y;
#pragma unroll
    for (int i = 0; i < 4; i++)
        tile[ty + i * 8][tx] = qkv[(long)(t0 + ty + i * 8) * 3072 + 2048 + d0 + tx];
    __syncthreads();
    int t = t0 + tx;
#pragma unroll
    for (int i = 0; i < 4; i++) {
        int d = d0 + ty + i * 8;
        vT[(long)d * TT + t] = tile[tx][ty + i * 8];
    }
}

// ---------------- causal softmax over bf16 scores, in-place, one block per row ----------------
__global__ __launch_bounds__(256) void softmax_kernel(bf16_t* __restrict__ S) {
    int i = blockIdx.x, h = blockIdx.y, tid = threadIdx.x;
    bf16_t* row = S + ((long)h * TT + i) * TT;
    int len = i + 1;
    float e[8];
    float mx = -1e30f;
#pragma unroll
    for (int jj = 0; jj < 8; jj++) {
        int j = tid + jj * 256;
        e[jj] = (j < len) ? (float)row[j] : -1e30f;
        mx = fmaxf(mx, e[jj]);
    }
    mx = block_reduce_max(mx);
    float sum = 0.0f;
#pragma unroll
    for (int jj = 0; jj < 8; jj++) {
        int j = tid + jj * 256;
        if (j < len) { e[jj] = __expf(e[jj] - mx); sum += e[jj]; } else e[jj] = 0.0f;
    }
    sum = block_reduce_sum(sum);
    float inv = 1.0f / sum;
#pragma unroll
    for (int jj = 0; jj < 8; jj++)
        row[tid + jj * 256] = (bf16_t)(e[jj] * inv);
}

// ---------------- generic bf16 MFMA GEMM: C[M][N] = A[M][K] * Bt[N][K]^T ----------------
// 128x128 tile, 4 waves (2x2), each wave 64x64 via 4x4 mfma_f32_16x16x32_bf16.
// m97-structure staging: global_load_lds width=16 into linear [128][32] LDS tiles.
// Grid: blockIdx.x = M-tile (FAST dim, few tiles -> consecutive blocks share the
// B-panel => L2/L3 reuse of the big N-side operand), blockIdx.y = N-tile.
// OOB rows are CLAMPED (not zero-filled): garbage rows only feed garbage output
// rows/cols which the epilogue masks. M is always a multiple of 128 here.
template <int OBF, int BIAS, int GELU, int RES>
__global__ __launch_bounds__(256, 2) void gemm_bt(
    const bf16_t* __restrict__ A, long sA, int lda,
    const bf16_t* __restrict__ Bt, long sB, int ldb,
    void* __restrict__ Cv, long sC, int ldc,
    const float* __restrict__ bias, const float* res,
    int M, int N, int K) {
    __shared__ bf16_t lA[128 * 32];
    __shared__ bf16_t lB[128 * 32];
    int bz = blockIdx.z;
    A += (long)bz * sA;
    Bt += (long)bz * sB;
    long cOff = (long)bz * sC;
    int m0 = blockIdx.x * 128, n0 = blockIdx.y * 128;
    int t = threadIdx.x;
    int wave = t >> 6, lane = t & 63;
    int wm = wave >> 1, wn = wave & 1;
    int lr = lane & 15, lq = lane >> 4;
    f32x4 acc[4][4];
#pragma unroll
    for (int a = 0; a < 4; a++)
#pragma unroll
        for (int b = 0; b < 4; b++) acc[a][b] = (f32x4){0.f, 0.f, 0.f, 0.f};

    // staging geometry: thread t covers 16B at LDS byte offset t*16 within each
    // 4KB half-tile; global source = row (t>>2), 16B-segment (t&3). Rows clamped.
    int rowHalf = wave * 16 + (lane >> 2);          // 0..63
    int seg8 = (lane & 3) * 8;                      // bf16 offset in a 32-wide row
    int rA0 = m0 + rowHalf;       if (rA0 > M - 1) rA0 = M - 1;
    int rA1 = m0 + rowHalf + 64;  if (rA1 > M - 1) rA1 = M - 1;
    int rB0 = n0 + rowHalf;       if (rB0 > N - 1) rB0 = N - 1;
    int rB1 = n0 + rowHalf + 64;  if (rB1 > N - 1) rB1 = N - 1;
    const bf16_t* gA0 = A + (long)rA0 * lda + seg8;
    const bf16_t* gA1 = A + (long)rA1 * lda + seg8;
    const bf16_t* gB0 = Bt + (long)rB0 * ldb + seg8;
    const bf16_t* gB1 = Bt + (long)rB1 * ldb + seg8;
    bf16_t* dA0 = lA + wave * 512;          // wave-uniform LDS bases
    bf16_t* dA1 = lA + 2048 + wave * 512;
    bf16_t* dB0 = lB + wave * 512;
    bf16_t* dB1 = lB + 2048 + wave * 512;

    for (int k0 = 0; k0 < K; k0 += 32) {
        __syncthreads();                    // prior iteration's ds_reads done
        async16(gA0 + k0, dA0);
        async16(gA1 + k0, dA1);
        async16(gB0 + k0, dB0);
        async16(gB1 + k0, dB1);
        __syncthreads();                    // drains vmcnt: tiles resident
        bf16x8 af[4], bfr[4];
#pragma unroll
        for (int mt = 0; mt < 4; mt++)
            af[mt] = *(const bf16x8*)&lA[(wm * 64 + mt * 16 + lr) * 32 + lq * 8];
#pragma unroll
        for (int nt = 0; nt < 4; nt++)
            bfr[nt] = *(const bf16x8*)&lB[(wn * 64 + nt * 16 + lr) * 32 + lq * 8];
#pragma unroll
        for (int mt = 0; mt < 4; mt++)
#pragma unroll
            for (int nt = 0; nt < 4; nt++)
                acc[mt][nt] = __builtin_amdgcn_mfma_f32_16x16x32_bf16(af[mt], bfr[nt], acc[mt][nt], 0, 0, 0);
    }
    // epilogue: D tile (mt,nt): row = lq*4+r, col = lr
#pragma unroll
    for (int nt = 0; nt < 4; nt++) {
        int col = n0 + wn * 64 + nt * 16 + lr;
        if (col >= N) continue;
        float bb = BIAS ? bias[col] : 0.0f;
#pragma unroll
        for (int mt = 0; mt < 4; mt++) {
            int rbase = m0 + wm * 64 + mt * 16 + lq * 4;
#pragma unroll
            for (int r = 0; r < 4; r++) {
                int rowi = rbase + r;
                if (rowi >= M) continue;
                float val = acc[mt][nt][r] + bb;
                if (GELU) val = 0.5f * val * (1.0f + erff(val * 0.70710678118f));
                if (RES) val += res[(long)rowi * ldc + col];
                long idx = cOff + (long)rowi * ldc + col;
                if (OBF) ((bf16_t*)Cv)[idx] = (bf16_t)val;
                else     ((float*)Cv)[idx] = val;
            }
        }
    }
}

extern "C" void kernel_launch(void* const* d_in, const int* in_sizes, int n_in,
                              void* d_out, int out_size, void* d_ws, size_t ws_size,
                              hipStream_t stream) {
    (void)in_sizes; (void)n_in; (void)out_size; (void)ws_size;
    const int*   ids  = (const int*)d_in[0];
    const float* emb  = (const float*)d_in[1];
    const float* Wq   = (const float*)d_in[2];
    const float* Wk   = (const float*)d_in[3];
    const float* Wv   = (const float*)d_in[4];
    const float* Wo   = (const float*)d_in[5];
    const float* ln1g = (const float*)d_in[6];
    const float* ln1b = (const float*)d_in[7];
    const float* ln2g = (const float*)d_in[8];
    const float* ln2b = (const float*)d_in[9];
    const float* W1   = (const float*)d_in[10];
    const float* b1   = (const float*)d_in[11];
    const float* W2   = (const float*)d_in[12];
    const float* b2   = (const float*)d_in[13];
    const float* lnfg = (const float*)d_in[14];
    const float* lnfb = (const float*)d_in[15];
    float* out = (float*)d_out;

    char* p = (char*)d_ws;
    size_t off = 0;
    auto alloc = [&](size_t bytes) -> void* {
        void* r = p + off;
        off += (bytes + 255) & ~(size_t)255;
        return r;
    };
    bf16_t* WqkvT = (bf16_t*)alloc((size_t)NL * 3072 * 1024 * 2);  // [L][3072][1024]
    bf16_t* WoT   = (bf16_t*)alloc((size_t)NL * 1024 * 1024 * 2);  // [L][1024][1024]
    bf16_t* W1T   = (bf16_t*)alloc((size_t)NL * 4096 * 1024 * 2);  // [L][4096][1024]
    bf16_t* W2T   = (bf16_t*)alloc((size_t)NL * 1024 * 4096 * 2);  // [L][1024][4096]
    bf16_t* embB  = (bf16_t*)alloc((size_t)VV * DD * 2);           // [V][1024]
    float*  x     = (float*)alloc((size_t)TT * DD * 4);
    bf16_t* hB    = (bf16_t*)alloc((size_t)TT * DD * 2);
    bf16_t* qkv   = (bf16_t*)alloc((size_t)TT * 3072 * 2);
    bf16_t* vT    = (bf16_t*)alloc((size_t)DD * TT * 2);           // [d][t]
    bf16_t* S     = (bf16_t*)alloc((size_t)NH * TT * TT * 2);      // [h][t][t]
    bf16_t* attn  = (bf16_t*)alloc((size_t)TT * DD * 2);
    bf16_t* mlp   = (bf16_t*)alloc((size_t)TT * DMLP * 2);

    dim3 tb(32, 8);
    // weight convert + transpose (every call: ws is re-poisoned)
    trans_w_kernel<<<dim3(32, 32, NL), tb, 0, stream>>>(Wq, WqkvT,                      1024, 1024, (long)1024 * 1024, (long)3072 * 1024);
    trans_w_kernel<<<dim3(32, 32, NL), tb, 0, stream>>>(Wk, WqkvT + (long)1024 * 1024,  1024, 1024, (long)1024 * 1024, (long)3072 * 1024);
    trans_w_kernel<<<dim3(32, 32, NL), tb, 0, stream>>>(Wv, WqkvT + (long)2048 * 1024,  1024, 1024, (long)1024 * 1024, (long)3072 * 1024);
    trans_w_kernel<<<dim3(32, 32, NL), tb, 0, stream>>>(Wo, WoT, 1024, 1024, (long)1024 * 1024, (long)1024 * 1024);
    trans_w_kernel<<<dim3(128, 32, NL), tb, 0, stream>>>(W1, W1T, 1024, 4096, (long)1024 * 4096, (long)4096 * 1024);
    trans_w_kernel<<<dim3(32, 128, NL), tb, 0, stream>>>(W2, W2T, 4096, 1024, (long)4096 * 1024, (long)1024 * 4096);

    long n4 = (long)VV * DD / 4;
    cvt_kernel<<<dim3((unsigned)((n4 + 255) / 256)), 256, 0, stream>>>(emb, embB, n4);
    gather_kernel<<<dim3(TT), 256, 0, stream>>>(ids, emb, x);

    for (int l = 0; l < NL; l++) {
        ln_kernel<<<TT, 256, 0, stream>>>(x, ln1g + l * DD, ln1b + l * DD, hB);
        // QKV fused: [2048][1024] x [3072][1024]^T -> qkv [2048][3072]
        gemm_bt<1, 0, 0, 0><<<dim3(16, 24, 1), 256, 0, stream>>>(
            hB, 0, 1024, WqkvT + (long)l * 3072 * 1024, 0, 1024,
            qkv, 0, 3072, nullptr, nullptr, 2048, 3072, 1024);
        rope_kernel<<<dim3(TT, 2), 256, 0, stream>>>(qkv);
        trans_v_kernel<<<dim3(64, 32), tb, 0, stream>>>(qkv, vT);
        // scores: per head, S[h] = Q_h [2048x64] * K_h^T  (scale folded into q)
        gemm_bt<1, 0, 0, 0><<<dim3(16, 16, NH), 256, 0, stream>>>(
            qkv, 64, 3072, qkv + 1024, 64, 3072,
            S, (long)TT * TT, TT, nullptr, nullptr, 2048, 2048, 64);
        softmax_kernel<<<dim3(TT, NH), 256, 0, stream>>>(S);
        // out: P [2048x2048] * vT[h] [64x2048]^T -> attn cols h*64..h*64+63
        gemm_bt<1, 0, 0, 0><<<dim3(16, 1, NH), 256, 0, stream>>>(
            S, (long)TT * TT, TT, vT, (long)HDIM * TT, TT,
            attn, HDIM, 1024, nullptr, nullptr, 2048, HDIM, 2048);
        // x += attn @ Wo
        gemm_bt<0, 0, 0, 1><<<dim3(16, 8, 1), 256, 0, stream>>>(
            attn, 0, 1024, WoT + (long)l * 1024 * 1024, 0, 1024,
            x, 0, 1024, nullptr, x, 2048, 1024, 1024);
        ln_kernel<<<TT, 256, 0, stream>>>(x, ln2g + l * DD, ln2b + l * DD, hB);
        // mlp = gelu(h @ W1 + b1)
        gemm_bt<1, 1, 1, 0><<<dim3(16, 32, 1), 256, 0, stream>>>(
            hB, 0, 1024, W1T + (long)l * 4096 * 1024, 0, 1024,
            mlp, 0, DMLP, b1 + (long)l * DMLP, nullptr, 2048, DMLP, 1024);
        // x += mlp @ W2 + b2
        gemm_bt<0, 1, 0, 1><<<dim3(16, 8, 1), 256, 0, stream>>>(
            mlp, 0, DMLP, W2T + (long)l * 1024 * 4096, 0, DMLP,
            x, 0, 1024, b2 + (long)l * DD, x, 2048, 1024, DMLP);
    }
    ln_kernel<<<TT, 256, 0, stream>>>(x, lnfg, lnfb, hB);
    // logits = xf @ emb^T : [2048][1024] x [50257][1024]^T
    gemm_bt<0, 0, 0, 0><<<dim3(16, (VV + 127) / 128, 1), 256, 0, stream>>>(
        hB, 0, 1024, embB, 0, 1024,
        out, 0, VV, nullptr, nullptr, 2048, VV, 1024);
}

// Round 2
// 2241.239 us; speedup vs baseline: 1.4472x; 1.1234x over previous
//
#include <hip/hip_runtime.h>
#include <hip/hip_bf16.h>
#include <math.h>

// GPT forward: B=1, T=2048, D=1024, L=4, H=16, HD=64, MLP=4096, V=50257
#define TT   2048
#define DD   1024
#define NL   4
#define NH   16
#define HDIM 64
#define VV   50257
#define DMLP 4096

typedef __bf16 bf16_t;
typedef __bf16 bf16x8 __attribute__((ext_vector_type(8)));
typedef __bf16 bf16x4 __attribute__((ext_vector_type(4)));
typedef float  f32x4  __attribute__((ext_vector_type(4)));

// ---------------- reductions (block = 256 = 4 waves) ----------------
__device__ inline float block_reduce_sum(float v) {
    __shared__ float sbuf[4];
#pragma unroll
    for (int o = 32; o > 0; o >>= 1) v += __shfl_down(v, o, 64);
    int w = threadIdx.x >> 6, lane = threadIdx.x & 63;
    __syncthreads();
    if (lane == 0) sbuf[w] = v;
    __syncthreads();
    return sbuf[0] + sbuf[1] + sbuf[2] + sbuf[3];
}

// ---------------- async global -> LDS, 16B per lane ----------------
__device__ __forceinline__ void async16(const bf16_t* g, bf16_t* l) {
    __builtin_amdgcn_global_load_lds(
        (const __attribute__((address_space(1))) unsigned int*)g,
        (__attribute__((address_space(3))) unsigned int*)l,
        16, 0, 0);
}

// ---------------- weight convert+transpose: W[K][N] f32 -> Wt[N][K] bf16 ----------------
__global__ void trans_w_kernel(const float* __restrict__ in, bf16_t* __restrict__ out,
                               int K, int N, long inStride, long outStride) {
    __shared__ float tile[32][33];
    long zin  = (long)blockIdx.z * inStride;
    long zout = (long)blockIdx.z * outStride;
    int tx = threadIdx.x, ty = threadIdx.y;
    int n = blockIdx.x * 32 + tx;
    int k0 = blockIdx.y * 32;
#pragma unroll
    for (int i = 0; i < 4; i++)
        tile[ty + i * 8][tx] = in[zin + (long)(k0 + ty + i * 8) * N + n];
    __syncthreads();
    int k = k0 + tx;
#pragma unroll
    for (int i = 0; i < 4; i++) {
        int nn = blockIdx.x * 32 + ty + i * 8;
        out[zout + (long)nn * K + k] = (bf16_t)tile[tx][ty + i * 8];
    }
}

// ---------------- f32 -> bf16 elementwise (x4) ----------------
__global__ void cvt_kernel(const float* __restrict__ in, bf16_t* __restrict__ out, long n4) {
    long i = (long)blockIdx.x * 256 + threadIdx.x;
    if (i >= n4) return;
    float4 v = *(const float4*)(in + i * 4);
    bf16x4 o;
    o[0] = (bf16_t)v.x; o[1] = (bf16_t)v.y; o[2] = (bf16_t)v.z; o[3] = (bf16_t)v.w;
    *(bf16x4*)(out + i * 4) = o;
}

// ---------------- embedding gather (fp32) ----------------
__global__ void gather_kernel(const int* __restrict__ ids, const float* __restrict__ emb,
                              float* __restrict__ x) {
    int row = blockIdx.x;
    int id = ids[row];
    const float4* src = (const float4*)(emb + (long)id * DD);
    float4* dst = (float4*)(x + (long)row * DD);
    dst[threadIdx.x] = src[threadIdx.x];
}

// ---------------- LayerNorm fp32 in -> bf16 out, one block per row ----------------
__global__ __launch_bounds__(256) void ln_kernel(const float* __restrict__ x,
                                                 const float* __restrict__ g,
                                                 const float* __restrict__ b,
                                                 bf16_t* __restrict__ out) {
    int row = blockIdx.x, tid = threadIdx.x;
    float4 v = *(const float4*)(x + (long)row * DD + tid * 4);
    float s = v.x + v.y + v.z + v.w;
    s = block_reduce_sum(s);
    float mean = s * (1.0f / DD);
    float dx = v.x - mean, dy = v.y - mean, dz = v.z - mean, dw = v.w - mean;
    float sq = dx * dx + dy * dy + dz * dz + dw * dw;
    sq = block_reduce_sum(sq);
    float inv = rsqrtf(sq * (1.0f / DD) + 1e-5f);
    float4 gv = *(const float4*)(g + tid * 4);
    float4 bv = *(const float4*)(b + tid * 4);
    bf16x4 o;
    o[0] = (bf16_t)(dx * inv * gv.x + bv.x);
    o[1] = (bf16_t)(dy * inv * gv.y + bv.y);
    o[2] = (bf16_t)(dz * inv * gv.z + bv.z);
    o[3] = (bf16_t)(dw * inv * gv.w + bv.w);
    *(bf16x4*)(out + (long)row * DD + tid * 4) = o;
}

// ---------------- RoPE on q,k (in-place, pairwise) + fold 1/sqrt(HD) into q ----------------
__global__ void rope_kernel(bf16_t* __restrict__ qkv) {
    int t = blockIdx.x;
    int pIdx = blockIdx.y * 256 + threadIdx.x;   // 0..511 : (head, i<32)
    int h = pIdx >> 5, i = pIdx & 31;
    float invf = powf(10000.0f, -(float)i * (1.0f / 32.0f));
    float ang = (float)t * invf;
    float s, c;
    sincosf(ang, &s, &c);
    long base = (long)t * 3072 + h * 64 + i;
    float q1 = (float)qkv[base], q2 = (float)qkv[base + 32];
    qkv[base]      = (bf16_t)((q1 * c - q2 * s) * 0.125f);
    qkv[base + 32] = (bf16_t)((q2 * c + q1 * s) * 0.125f);
    float k1 = (float)qkv[base + 1024], k2 = (float)qkv[base + 1056];
    qkv[base + 1024] = (bf16_t)(k1 * c - k2 * s);
    qkv[base + 1056] = (bf16_t)(k2 * c + k1 * s);
}

// ---------------- per-head V transpose: v[t][d] -> vT[d][t] (d = h*64+dd) ----------------
__global__ void trans_v_kernel(const bf16_t* __restrict__ qkv, bf16_t* __restrict__ vT) {
    __shared__ bf16_t tile[32][33];
    int t0 = blockIdx.x * 32, d0 = blockIdx.y * 32;
    int tx = threadIdx.x, ty = threadIdx.y;
#pragma unroll
    for (int i = 0; i < 4; i++)
        tile[ty + i * 8][tx] = qkv[(long)(t0 + ty + i * 8) * 3072 + 2048 + d0 + tx];
    __syncthreads();
    int t = t0 + tx;
#pragma unroll
    for (int i = 0; i < 4; i++) {
        int d = d0 + ty + i * 8;
        vT[(long)d * TT + t] = tile[tx][ty + i * 8];
    }
}

// ---------------- fused causal flash attention ----------------
// Grid (32, 16): x = q-tile (reversed for load balance), y = head.
// Block = 256 = 4 waves; wave w owns q rows q0+w*16 .. +15.
// Per 64-kv step: K,V^T staged via global_load_lds into seg-planed LDS
// ([8 segs][64 rows][16B] -> B-frag ds_read_b128 is conflict-free), S computed
// in f32 by MFMA, online softmax via 16-lane shfl_xor butterflies, P re-laid
// C-frag -> A-frag through a per-wave LDS buffer, O accumulated in registers.
__global__ __launch_bounds__(256) void flash_kernel(const bf16_t* __restrict__ qkv,
                                                    const bf16_t* __restrict__ vT,
                                                    bf16_t* __restrict__ attn) {
    __shared__ bf16_t lK[4096];   // [seg(8)][row(64)][8 elems]
    __shared__ bf16_t lV[4096];   // [seg(8)][d(64)][8 elems]
    __shared__ bf16_t lP[4096];   // per-wave 1024: [seg(8)][row(16)][8 elems]
    int qt = 31 - blockIdx.x;
    int h  = blockIdx.y;
    int t  = threadIdx.x;
    int w = t >> 6, lane = t & 63;
    int lr = lane & 15, lq = lane >> 4;
    int q0 = qt * 64;

    // Q fragments: row = q0 + w*16 + lr, k = kf*32 + lq*8 (scale folded by rope)
    const bf16_t* qrow = qkv + (long)(q0 + w * 16 + lr) * 3072 + h * 64;
    bf16x8 qf0 = *(const bf16x8*)(qrow + lq * 8);
    bf16x8 qf1 = *(const bf16x8*)(qrow + 32 + lq * 8);

    const bf16_t* gK = qkv + 1024 + h * 64 + (long)lane * 3072;  // + kv0*3072 + seg*8
    const bf16_t* gV = vT + (long)(h * 64 + lane) * 2048;        // + kv0 + seg*8

    bf16_t* dK0 = lK + w * 512;          // stages seg w   (rows = lane)
    bf16_t* dK1 = lK + w * 512 + 2048;   // stages seg w+4
    bf16_t* dV0 = lV + w * 512;
    bf16_t* dV1 = lV + w * 512 + 2048;
    bf16_t* wP  = lP + w * 1024;

    f32x4 o[4];
    float m[4], l[4];
#pragma unroll
    for (int i = 0; i < 4; i++) { o[i] = (f32x4){0.f, 0.f, 0.f, 0.f}; m[i] = -1e30f; l[i] = 0.f; }

    for (int st = 0; st <= qt; st++) {
        long kv = (long)st * 64;
        __syncthreads();                          // prior step's K/V reads done
        async16(gK + kv * 3072 + w * 8, dK0);
        async16(gK + kv * 3072 + (w + 4) * 8, dK1);
        async16(gV + kv + w * 8, dV0);
        async16(gV + kv + (w + 4) * 8, dV1);
        __syncthreads();                          // drains vmcnt: K/V resident

        // S = Q K^T  (rows q, cols kv; C-layout row=lq*4+r col=lr)
        f32x4 s[4];
#pragma unroll
        for (int nt = 0; nt < 4; nt++) {
            s[nt] = (f32x4){0.f, 0.f, 0.f, 0.f};
            bf16x8 kb0 = *(const bf16x8*)&lK[lq * 512 + (nt * 16 + lr) * 8];
            bf16x8 kb1 = *(const bf16x8*)&lK[(4 + lq) * 512 + (nt * 16 + lr) * 8];
            s[nt] = __builtin_amdgcn_mfma_f32_16x16x32_bf16(qf0, kb0, s[nt], 0, 0, 0);
            s[nt] = __builtin_amdgcn_mfma_f32_16x16x32_bf16(qf1, kb1, s[nt], 0, 0, 0);
        }
        if (st == qt) {   // diagonal block: mask col > row
#pragma unroll
            for (int nt = 0; nt < 4; nt++)
#pragma unroll
                for (int r = 0; r < 4; r++)
                    if (nt * 16 + lr > w * 16 + lq * 4 + r) s[nt][r] = -1e30f;
        }
        // online softmax (row stats across the 16-lane col group)
        float pm[4];
#pragma unroll
        for (int r = 0; r < 4; r++)
            pm[r] = fmaxf(fmaxf(s[0][r], s[1][r]), fmaxf(s[2][r], s[3][r]));
#pragma unroll
        for (int msk = 8; msk >= 1; msk >>= 1)
#pragma unroll
            for (int r = 0; r < 4; r++)
                pm[r] = fmaxf(pm[r], __shfl_xor(pm[r], msk));
        float f[4];
#pragma unroll
        for (int r = 0; r < 4; r++) {
            float nm = fmaxf(m[r], pm[r]);
            f[r] = __expf(m[r] - nm);
            m[r] = nm;
        }
        float ps[4] = {0.f, 0.f, 0.f, 0.f};
#pragma unroll
        for (int nt = 0; nt < 4; nt++)
#pragma unroll
            for (int r = 0; r < 4; r++) {
                float p = __expf(s[nt][r] - m[r]);
                ps[r] += p;
                wP[((nt * 16 + lr) >> 3) * 128 + (lq * 4 + r) * 8 + (lr & 7)] = (bf16_t)p;
            }
#pragma unroll
        for (int msk = 8; msk >= 1; msk >>= 1)
#pragma unroll
            for (int r = 0; r < 4; r++)
                ps[r] += __shfl_xor(ps[r], msk);
#pragma unroll
        for (int r = 0; r < 4; r++) l[r] = l[r] * f[r] + ps[r];
#pragma unroll
        for (int nt = 0; nt < 4; nt++)
#pragma unroll
            for (int r = 0; r < 4; r++) o[nt][r] *= f[r];
        // PV: A = P (row=q-within-16, k=kv), B = V^T (row=d, k=kv)
        bf16x8 pa0 = *(const bf16x8*)&wP[lq * 128 + lr * 8];
        bf16x8 pa1 = *(const bf16x8*)&wP[(4 + lq) * 128 + lr * 8];
#pragma unroll
        for (int nt = 0; nt < 4; nt++) {
            bf16x8 vb0 = *(const bf16x8*)&lV[lq * 512 + (nt * 16 + lr) * 8];
            bf16x8 vb1 = *(const bf16x8*)&lV[(4 + lq) * 512 + (nt * 16 + lr) * 8];
            o[nt] = __builtin_amdgcn_mfma_f32_16x16x32_bf16(pa0, vb0, o[nt], 0, 0, 0);
            o[nt] = __builtin_amdgcn_mfma_f32_16x16x32_bf16(pa1, vb1, o[nt], 0, 0, 0);
        }
    }
    // epilogue: attn[q][h*64+d] = O / l
#pragma unroll
    for (int r = 0; r < 4; r++) {
        float inv = 1.0f / l[r];
        long row = q0 + w * 16 + lq * 4 + r;
#pragma unroll
        for (int nt = 0; nt < 4; nt++)
            attn[row * 1024 + h * 64 + nt * 16 + lr] = (bf16_t)(o[nt][r] * inv);
    }
}

// ---------------- generic bf16 MFMA GEMM: C[M][N] = A[M][K] * Bt[N][K]^T ----------------
// 128x128 tile, 4 waves (2x2), each wave 64x64 via 4x4 mfma_f32_16x16x32_bf16.
// m97-structure staging: global_load_lds width=16 into linear [128][32] LDS tiles.
// Grid: blockIdx.x = M-tile (FAST dim), blockIdx.y = N-tile (B-panel L2 reuse).
template <int OBF, int BIAS, int GELU, int RES>
__global__ __launch_bounds__(256, 2) void gemm_bt(
    const bf16_t* __restrict__ A, long sA, int lda,
    const bf16_t* __restrict__ Bt, long sB, int ldb,
    void* __restrict__ Cv, long sC, int ldc,
    const float* __restrict__ bias, const float* res,
    int M, int N, int K) {
    __shared__ bf16_t lA[128 * 32];
    __shared__ bf16_t lB[128 * 32];
    int bz = blockIdx.z;
    A += (long)bz * sA;
    Bt += (long)bz * sB;
    long cOff = (long)bz * sC;
    int m0 = blockIdx.x * 128, n0 = blockIdx.y * 128;
    int t = threadIdx.x;
    int wave = t >> 6, lane = t & 63;
    int wm = wave >> 1, wn = wave & 1;
    int lr = lane & 15, lq = lane >> 4;
    f32x4 acc[4][4];
#pragma unroll
    for (int a = 0; a < 4; a++)
#pragma unroll
        for (int b = 0; b < 4; b++) acc[a][b] = (f32x4){0.f, 0.f, 0.f, 0.f};

    int rowHalf = wave * 16 + (lane >> 2);          // 0..63
    int seg8 = (lane & 3) * 8;
    int rA0 = m0 + rowHalf;       if (rA0 > M - 1) rA0 = M - 1;
    int rA1 = m0 + rowHalf + 64;  if (rA1 > M - 1) rA1 = M - 1;
    int rB0 = n0 + rowHalf;       if (rB0 > N - 1) rB0 = N - 1;
    int rB1 = n0 + rowHalf + 64;  if (rB1 > N - 1) rB1 = N - 1;
    const bf16_t* gA0 = A + (long)rA0 * lda + seg8;
    const bf16_t* gA1 = A + (long)rA1 * lda + seg8;
    const bf16_t* gB0 = Bt + (long)rB0 * ldb + seg8;
    const bf16_t* gB1 = Bt + (long)rB1 * ldb + seg8;
    bf16_t* dA0 = lA + wave * 512;
    bf16_t* dA1 = lA + 2048 + wave * 512;
    bf16_t* dB0 = lB + wave * 512;
    bf16_t* dB1 = lB + 2048 + wave * 512;

    for (int k0 = 0; k0 < K; k0 += 32) {
        __syncthreads();
        async16(gA0 + k0, dA0);
        async16(gA1 + k0, dA1);
        async16(gB0 + k0, dB0);
        async16(gB1 + k0, dB1);
        __syncthreads();
        bf16x8 af[4], bfr[4];
#pragma unroll
        for (int mt = 0; mt < 4; mt++)
            af[mt] = *(const bf16x8*)&lA[(wm * 64 + mt * 16 + lr) * 32 + lq * 8];
#pragma unroll
        for (int nt = 0; nt < 4; nt++)
            bfr[nt] = *(const bf16x8*)&lB[(wn * 64 + nt * 16 + lr) * 32 + lq * 8];
#pragma unroll
        for (int mt = 0; mt < 4; mt++)
#pragma unroll
            for (int nt = 0; nt < 4; nt++)
                acc[mt][nt] = __builtin_amdgcn_mfma_f32_16x16x32_bf16(af[mt], bfr[nt], acc[mt][nt], 0, 0, 0);
    }
#pragma unroll
    for (int nt = 0; nt < 4; nt++) {
        int col = n0 + wn * 64 + nt * 16 + lr;
        if (col >= N) continue;
        float bb = BIAS ? bias[col] : 0.0f;
#pragma unroll
        for (int mt = 0; mt < 4; mt++) {
            int rbase = m0 + wm * 64 + mt * 16 + lq * 4;
#pragma unroll
            for (int r = 0; r < 4; r++) {
                int rowi = rbase + r;
                if (rowi >= M) continue;
                float val = acc[mt][nt][r] + bb;
                if (GELU) val = 0.5f * val * (1.0f + erff(val * 0.70710678118f));
                if (RES) val += res[(long)rowi * ldc + col];
                long idx = cOff + (long)rowi * ldc + col;
                if (OBF) ((bf16_t*)Cv)[idx] = (bf16_t)val;
                else     ((float*)Cv)[idx] = val;
            }
        }
    }
}

extern "C" void kernel_launch(void* const* d_in, const int* in_sizes, int n_in,
                              void* d_out, int out_size, void* d_ws, size_t ws_size,
                              hipStream_t stream) {
    (void)in_sizes; (void)n_in; (void)out_size; (void)ws_size;
    const int*   ids  = (const int*)d_in[0];
    const float* emb  = (const float*)d_in[1];
    const float* Wq   = (const float*)d_in[2];
    const float* Wk   = (const float*)d_in[3];
    const float* Wv   = (const float*)d_in[4];
    const float* Wo   = (const float*)d_in[5];
    const float* ln1g = (const float*)d_in[6];
    const float* ln1b = (const float*)d_in[7];
    const float* ln2g = (const float*)d_in[8];
    const float* ln2b = (const float*)d_in[9];
    const float* W1   = (const float*)d_in[10];
    const float* b1   = (const float*)d_in[11];
    const float* W2   = (const float*)d_in[12];
    const float* b2   = (const float*)d_in[13];
    const float* lnfg = (const float*)d_in[14];
    const float* lnfb = (const float*)d_in[15];
    float* out = (float*)d_out;

    char* p = (char*)d_ws;
    size_t off = 0;
    auto alloc = [&](size_t bytes) -> void* {
        void* r = p + off;
        off += (bytes + 255) & ~(size_t)255;
        return r;
    };
    bf16_t* WqkvT = (bf16_t*)alloc((size_t)NL * 3072 * 1024 * 2);  // [L][3072][1024]
    bf16_t* WoT   = (bf16_t*)alloc((size_t)NL * 1024 * 1024 * 2);  // [L][1024][1024]
    bf16_t* W1T   = (bf16_t*)alloc((size_t)NL * 4096 * 1024 * 2);  // [L][4096][1024]
    bf16_t* W2T   = (bf16_t*)alloc((size_t)NL * 1024 * 4096 * 2);  // [L][1024][4096]
    bf16_t* embB  = (bf16_t*)alloc((size_t)VV * DD * 2);           // [V][1024]
    float*  x     = (float*)alloc((size_t)TT * DD * 4);
    bf16_t* hB    = (bf16_t*)alloc((size_t)TT * DD * 2);
    bf16_t* qkv   = (bf16_t*)alloc((size_t)TT * 3072 * 2);
    bf16_t* vT    = (bf16_t*)alloc((size_t)DD * TT * 2);           // [d][t]
    bf16_t* attn  = (bf16_t*)alloc((size_t)TT * DD * 2);
    bf16_t* mlp   = (bf16_t*)alloc((size_t)TT * DMLP * 2);

    dim3 tb(32, 8);
    // weight convert + transpose (every call: ws is re-poisoned)
    trans_w_kernel<<<dim3(32, 32, NL), tb, 0, stream>>>(Wq, WqkvT,                      1024, 1024, (long)1024 * 1024, (long)3072 * 1024);
    trans_w_kernel<<<dim3(32, 32, NL), tb, 0, stream>>>(Wk, WqkvT + (long)1024 * 1024,  1024, 1024, (long)1024 * 1024, (long)3072 * 1024);
    trans_w_kernel<<<dim3(32, 32, NL), tb, 0, stream>>>(Wv, WqkvT + (long)2048 * 1024,  1024, 1024, (long)1024 * 1024, (long)3072 * 1024);
    trans_w_kernel<<<dim3(32, 32, NL), tb, 0, stream>>>(Wo, WoT, 1024, 1024, (long)1024 * 1024, (long)1024 * 1024);
    trans_w_kernel<<<dim3(128, 32, NL), tb, 0, stream>>>(W1, W1T, 1024, 4096, (long)1024 * 4096, (long)4096 * 1024);
    trans_w_kernel<<<dim3(32, 128, NL), tb, 0, stream>>>(W2, W2T, 4096, 1024, (long)4096 * 1024, (long)1024 * 4096);

    long n4 = (long)VV * DD / 4;
    cvt_kernel<<<dim3((unsigned)((n4 + 255) / 256)), 256, 0, stream>>>(emb, embB, n4);
    gather_kernel<<<dim3(TT), 256, 0, stream>>>(ids, emb, x);

    for (int l = 0; l < NL; l++) {
        ln_kernel<<<TT, 256, 0, stream>>>(x, ln1g + l * DD, ln1b + l * DD, hB);
        // QKV fused: [2048][1024] x [3072][1024]^T -> qkv [2048][3072]
        gemm_bt<1, 0, 0, 0><<<dim3(16, 24, 1), 256, 0, stream>>>(
            hB, 0, 1024, WqkvT + (long)l * 3072 * 1024, 0, 1024,
            qkv, 0, 3072, nullptr, nullptr, 2048, 3072, 1024);
        rope_kernel<<<dim3(TT, 2), 256, 0, stream>>>(qkv);
        trans_v_kernel<<<dim3(64, 32), tb, 0, stream>>>(qkv, vT);
        // fused flash attention: qkv + vT -> attn
        flash_kernel<<<dim3(32, NH), 256, 0, stream>>>(qkv, vT, attn);
        // x += attn @ Wo
        gemm_bt<0, 0, 0, 1><<<dim3(16, 8, 1), 256, 0, stream>>>(
            attn, 0, 1024, WoT + (long)l * 1024 * 1024, 0, 1024,
            x, 0, 1024, nullptr, x, 2048, 1024, 1024);
        ln_kernel<<<TT, 256, 0, stream>>>(x, ln2g + l * DD, ln2b + l * DD, hB);
        // mlp = gelu(h @ W1 + b1)
        gemm_bt<1, 1, 1, 0><<<dim3(16, 32, 1), 256, 0, stream>>>(
            hB, 0, 1024, W1T + (long)l * 4096 * 1024, 0, 1024,
            mlp, 0, DMLP, b1 + (long)l * DMLP, nullptr, 2048, DMLP, 1024);
        // x += mlp @ W2 + b2
        gemm_bt<0, 1, 0, 1><<<dim3(16, 8, 1), 256, 0, stream>>>(
            mlp, 0, DMLP, W2T + (long)l * 1024 * 4096, 0, DMLP,
            x, 0, 1024, b2 + (long)l * DD, x, 2048, 1024, DMLP);
    }
    ln_kernel<<<TT, 256, 0, stream>>>(x, lnfg, lnfb, hB);
    // logits = xf @ emb^T : [2048][1024] x [50257][1024]^T
    gemm_bt<0, 0, 0, 0><<<dim3(16, (VV + 127) / 128, 1), 256, 0, stream>>>(
        hB, 0, 1024, embB, 0, 1024,
        out, 0, VV, nullptr, nullptr, 2048, VV, 1024);
}